// Round 2
// baseline (1481.848 us; speedup 1.0000x reference)
//
#include <hip/hip_runtime.h>

typedef __bf16 bf16x8 __attribute__((ext_vector_type(8)));
typedef float f32x4 __attribute__((ext_vector_type(4)));

#define MFMA16(a, b, c) __builtin_amdgcn_mfma_f32_16x16x32_bf16((a), (b), (c), 0, 0, 0)

// dims
#define NB 2
#define NC 512
#define NH 96
#define NW 320
#define PH 30720      // NH*NW pixels per batch
#define NPIX 61440    // NB*PH
#define NOUT 256

__device__ __forceinline__ unsigned short f2bf(float f) {
    union { float f; unsigned u; } v; v.f = f;
    unsigned r = v.u + 0x7fffu + ((v.u >> 16) & 1u);
    return (unsigned short)(r >> 16);
}

// ---------------- weight cast f32 -> bf16 ----------------
__global__ void k_cast(const float* __restrict__ src, unsigned short* __restrict__ dst, int n) {
    int i = blockIdx.x * 256 + threadIdx.x;
    if (i < n) dst[i] = f2bf(src[i]);
}

// ---------------- transpose [b,c,hw] f32 -> [b,hw,c] bf16 ----------------
__global__ __launch_bounds__(256) void k_transpose(
        const float* __restrict__ L, const float* __restrict__ R,
        unsigned short* __restrict__ Lcl, unsigned short* __restrict__ Rcl) {
    __shared__ float t[64][65];
    int z = blockIdx.z;                 // which*2 + b
    int b = z & 1, which = z >> 1;
    const float* src = which ? R : L;
    unsigned short* dst = which ? Rcl : Lcl;
    int c0 = blockIdx.y * 64;
    int p0 = blockIdx.x * 64;
    int tx = threadIdx.x & 63, ty = threadIdx.x >> 6;
#pragma unroll
    for (int i = 0; i < 16; ++i) {
        int cl = ty + i * 4;
        t[cl][tx] = src[(b * NC + c0 + cl) * PH + p0 + tx];
    }
    __syncthreads();
#pragma unroll
    for (int i = 0; i < 16; ++i) {
        int pl = ty + i * 4;
        dst[(b * PH + p0 + pl) * NC + c0 + tx] = f2bf(t[tx][pl]);
    }
}

// ---------------- QKV projection GEMM ----------------
// C[p, o] = sum_c A_cl[p, c] * W[o, c].  block tile: 64 p x 128 o, 4 waves.
// which==2 (V): store transposed to Vt[b][h][c][x]
__global__ __launch_bounds__(256) void k_proj(
        const unsigned short* __restrict__ Lcl, const unsigned short* __restrict__ Rcl,
        const unsigned short* __restrict__ Wq, const unsigned short* __restrict__ Wk,
        const unsigned short* __restrict__ Wv,
        unsigned short* __restrict__ Q, unsigned short* __restrict__ K,
        unsigned short* __restrict__ Vt) {
    int which = blockIdx.z;
    const unsigned short* A = (which == 0) ? Lcl : Rcl;
    const unsigned short* Wt = (which == 0) ? Wq : (which == 1) ? Wk : Wv;
    int pbase = blockIdx.x * 64;
    int obase = blockIdx.y * 128;
    int lane = threadIdx.x & 63, w = threadIdx.x >> 6;
    int lr = lane & 15, lg = lane >> 4;
    f32x4 acc[8] = {};
    int arow = pbase + w * 16 + lr;
#pragma unroll
    for (int kc = 0; kc < 16; ++kc) {
        bf16x8 af = *reinterpret_cast<const bf16x8*>(A + arow * NC + kc * 32 + lg * 8);
#pragma unroll
        for (int nf = 0; nf < 8; ++nf) {
            bf16x8 bfr = *reinterpret_cast<const bf16x8*>(Wt + (obase + nf * 16 + lr) * NC + kc * 32 + lg * 8);
            acc[nf] = MFMA16(af, bfr, acc[nf]);
        }
    }
    if (which < 2) {
        unsigned short* D = (which == 0) ? Q : K;
#pragma unroll
        for (int nf = 0; nf < 8; ++nf)
#pragma unroll
            for (int r = 0; r < 4; ++r) {
                int prow = pbase + w * 16 + lg * 4 + r;
                D[prow * NC + obase + nf * 16 + lr] = f2bf(acc[nf][r]);
            }
    } else {
#pragma unroll
        for (int nf = 0; nf < 8; ++nf)
#pragma unroll
            for (int r = 0; r < 4; ++r) {
                int prow = pbase + w * 16 + lg * 4 + r;
                int b = prow / PH, ph = prow % PH;
                int hh = ph / NW, x = ph % NW;
                Vt[((b * NH + hh) * NC + obase + nf * 16 + lr) * NW + x] = f2bf(acc[nf][r]);
            }
    }
}

// ---------------- attention: per (b,h), 64 q-rows per block ----------------
__global__ __launch_bounds__(256) void k_attn(
        const unsigned short* __restrict__ Q, const unsigned short* __restrict__ K,
        const unsigned short* __restrict__ Vt, unsigned short* __restrict__ O) {
    __shared__ unsigned short P[64][328];
    int qt = blockIdx.x, hh = blockIdx.y, b = blockIdx.z;
    int lane = threadIdx.x & 63, w = threadIdx.x >> 6;
    int lr = lane & 15, lg = lane >> 4;
    int rowbase = b * PH + hh * NW;     // pixel index of (b,h, x=0)
    int qrow = rowbase + qt * 64 + w * 16 + lr;

    bf16x8 qf[16];
#pragma unroll
    for (int kc = 0; kc < 16; ++kc)
        qf[kc] = *reinterpret_cast<const bf16x8*>(Q + qrow * NC + kc * 32 + lg * 8);

    f32x4 acc[20];
#pragma unroll
    for (int xt = 0; xt < 20; ++xt) acc[xt] = f32x4{0.f, 0.f, 0.f, 0.f};
#pragma unroll
    for (int xt = 0; xt < 20; ++xt) {
        int krow = rowbase + xt * 16 + lr;
#pragma unroll
        for (int kc = 0; kc < 16; ++kc) {
            bf16x8 kf = *reinterpret_cast<const bf16x8*>(K + krow * NC + kc * 32 + lg * 8);
            acc[xt] = MFMA16(qf[kc], kf, acc[xt]);
        }
    }
    // scale
#pragma unroll
    for (int xt = 0; xt < 20; ++xt)
#pragma unroll
        for (int r = 0; r < 4; ++r) acc[xt][r] *= 0.125f;
    // row max (rows lg*4+r live on the 16 lanes sharing lg)
    float m[4] = {-1e30f, -1e30f, -1e30f, -1e30f};
#pragma unroll
    for (int xt = 0; xt < 20; ++xt)
#pragma unroll
        for (int r = 0; r < 4; ++r) m[r] = fmaxf(m[r], acc[xt][r]);
#pragma unroll
    for (int mask = 1; mask < 16; mask <<= 1)
#pragma unroll
        for (int r = 0; r < 4; ++r) m[r] = fmaxf(m[r], __shfl_xor(m[r], mask));
    // exp + row sum
    float s[4] = {0.f, 0.f, 0.f, 0.f};
#pragma unroll
    for (int xt = 0; xt < 20; ++xt)
#pragma unroll
        for (int r = 0; r < 4; ++r) {
            float e = __expf(acc[xt][r] - m[r]);
            acc[xt][r] = e;
            s[r] += e;
        }
#pragma unroll
    for (int mask = 1; mask < 16; mask <<= 1)
#pragma unroll
        for (int r = 0; r < 4; ++r) s[r] += __shfl_xor(s[r], mask);
    // P -> LDS (unnormalized)
#pragma unroll
    for (int xt = 0; xt < 20; ++xt)
#pragma unroll
        for (int r = 0; r < 4; ++r)
            P[w * 16 + lg * 4 + r][xt * 16 + lr] = f2bf(acc[xt][r]);
    __syncthreads();

    bf16x8 pf[10];
#pragma unroll
    for (int kt = 0; kt < 10; ++kt)
        pf[kt] = *reinterpret_cast<const bf16x8*>(&P[w * 16 + lr][kt * 32 + lg * 8]);

    int vbase = (b * NH + hh) * NC;
#pragma unroll
    for (int ct = 0; ct < 32; ++ct) {
        f32x4 o4 = {0.f, 0.f, 0.f, 0.f};
#pragma unroll
        for (int kt = 0; kt < 10; ++kt) {
            bf16x8 vf = *reinterpret_cast<const bf16x8*>(Vt + (vbase + ct * 16 + lr) * NW + kt * 32 + lg * 8);
            o4 = MFMA16(pf[kt], vf, o4);
        }
#pragma unroll
        for (int r = 0; r < 4; ++r) {
            int prow = rowbase + qt * 64 + w * 16 + lg * 4 + r;
            O[prow * NC + ct * 16 + lr] = f2bf(o4[r] / s[r]);
        }
    }
}

// ---------------- w1 GEMM (K=1024 over concat) + BN + LeakyReLU ----------------
__global__ __launch_bounds__(256) void k_w1(
        const unsigned short* __restrict__ Lcl, const unsigned short* __restrict__ AO,
        const unsigned short* __restrict__ W1,
        const float* __restrict__ g, const float* __restrict__ be,
        const float* __restrict__ mu, const float* __restrict__ va,
        unsigned short* __restrict__ Y) {
    int pbase = blockIdx.x * 64, obase = blockIdx.y * 64;
    int lane = threadIdx.x & 63, w = threadIdx.x >> 6;
    int lr = lane & 15, lg = lane >> 4;
    f32x4 acc[4] = {};
    int arow = pbase + w * 16 + lr;
#pragma unroll
    for (int kc = 0; kc < 32; ++kc) {
        const unsigned short* Ap = (kc < 16) ? (Lcl + arow * NC + kc * 32) : (AO + arow * NC + (kc - 16) * 32);
        bf16x8 af = *reinterpret_cast<const bf16x8*>(Ap + lg * 8);
#pragma unroll
        for (int nf = 0; nf < 4; ++nf) {
            bf16x8 bfr = *reinterpret_cast<const bf16x8*>(W1 + (obase + nf * 16 + lr) * 1024 + kc * 32 + lg * 8);
            acc[nf] = MFMA16(af, bfr, acc[nf]);
        }
    }
#pragma unroll
    for (int nf = 0; nf < 4; ++nf) {
        int o = obase + nf * 16 + lr;
        float sc = g[o] * rsqrtf(va[o] + 1e-5f);
        float sh = be[o] - mu[o] * sc;
#pragma unroll
        for (int r = 0; r < 4; ++r) {
            int prow = pbase + w * 16 + lg * 4 + r;
            float y = acc[nf][r] * sc + sh;
            y = (y >= 0.f) ? y : 0.2f * y;
            Y[prow * NOUT + o] = f2bf(y);
        }
    }
}

// ---------------- w2 GEMM, computed transposed (m=o, n=pix) for coalesced store ----------------
__global__ __launch_bounds__(256) void k_w2(
        const unsigned short* __restrict__ Y, const unsigned short* __restrict__ W2,
        float* __restrict__ Out) {
    int obase = blockIdx.x * 64, pbase = blockIdx.y * 64;
    int lane = threadIdx.x & 63, w = threadIdx.x >> 6;
    int lr = lane & 15, lg = lane >> 4;
    f32x4 acc[4] = {};
    int orow = obase + w * 16 + lr;
#pragma unroll
    for (int kc = 0; kc < 8; ++kc) {
        bf16x8 af = *reinterpret_cast<const bf16x8*>(W2 + orow * NOUT + kc * 32 + lg * 8);
#pragma unroll
        for (int nf = 0; nf < 4; ++nf) {
            bf16x8 bfr = *reinterpret_cast<const bf16x8*>(Y + (pbase + nf * 16 + lr) * NOUT + kc * 32 + lg * 8);
            acc[nf] = MFMA16(af, bfr, acc[nf]);
        }
    }
#pragma unroll
    for (int nf = 0; nf < 4; ++nf)
#pragma unroll
        for (int r = 0; r < 4; ++r) {
            int o = obase + w * 16 + lg * 4 + r;
            int p = pbase + nf * 16 + lr;
            int b = p / PH, ph = p % PH;
            Out[(b * NOUT + o) * PH + ph] = acc[nf][r];
        }
}

extern "C" void kernel_launch(void* const* d_in, const int* in_sizes, int n_in,
                              void* d_out, int out_size, void* d_ws, size_t ws_size,
                              hipStream_t stream) {
    const float* left  = (const float*)d_in[0];
    const float* right = (const float*)d_in[1];
    const float* wq = (const float*)d_in[2];
    const float* wk = (const float*)d_in[3];
    const float* wv = (const float*)d_in[4];
    const float* w1 = (const float*)d_in[5];
    const float* bn_g = (const float*)d_in[6];
    const float* bn_b = (const float*)d_in[7];
    const float* bn_m = (const float*)d_in[8];
    const float* bn_v = (const float*)d_in[9];
    const float* w2 = (const float*)d_in[10];
    float* out = (float*)d_out;

    size_t off = 0;
    auto alloc = [&](size_t bytes) -> void* {
        void* p = (char*)d_ws + off;
        off += (bytes + 255) & ~(size_t)255;
        return p;
    };
    const size_t clb = (size_t)NPIX * NC * 2;        // 62.9 MB
    unsigned short* Lcl = (unsigned short*)alloc(clb);
    unsigned short* Rcl = (unsigned short*)alloc(clb);
    unsigned short* Qb  = (unsigned short*)alloc(clb);
    unsigned short* Kb  = (unsigned short*)alloc(clb);
    unsigned short* Vt  = (unsigned short*)alloc(clb);
    unsigned short* Wqb = (unsigned short*)alloc((size_t)NC * NC * 2);
    unsigned short* Wkb = (unsigned short*)alloc((size_t)NC * NC * 2);
    unsigned short* Wvb = (unsigned short*)alloc((size_t)NC * NC * 2);
    unsigned short* W1b = (unsigned short*)alloc((size_t)NOUT * 1024 * 2);
    unsigned short* W2b = (unsigned short*)alloc((size_t)NOUT * NOUT * 2);
    unsigned short* AO = Rcl;   // attention output aliases Rcl (dead after projections)
    unsigned short* Yb = Qb;    // y aliases Qb (dead after attention)

    k_cast<<<dim3((NC * NC + 255) / 256), 256, 0, stream>>>(wq, Wqb, NC * NC);
    k_cast<<<dim3((NC * NC + 255) / 256), 256, 0, stream>>>(wk, Wkb, NC * NC);
    k_cast<<<dim3((NC * NC + 255) / 256), 256, 0, stream>>>(wv, Wvb, NC * NC);
    k_cast<<<dim3((NOUT * 1024 + 255) / 256), 256, 0, stream>>>(w1, W1b, NOUT * 1024);
    k_cast<<<dim3((NOUT * NOUT + 255) / 256), 256, 0, stream>>>(w2, W2b, NOUT * NOUT);

    k_transpose<<<dim3(PH / 64, NC / 64, 4), 256, 0, stream>>>(left, right, Lcl, Rcl);

    k_proj<<<dim3(NPIX / 64, 4, 3), 256, 0, stream>>>(Lcl, Rcl, Wqb, Wkb, Wvb, Qb, Kb, Vt);

    k_attn<<<dim3(NW / 64, NH, NB), 256, 0, stream>>>(Qb, Kb, Vt, AO);

    k_w1<<<dim3(NPIX / 64, NOUT / 64), 256, 0, stream>>>(Lcl, AO, W1b, bn_g, bn_b, bn_m, bn_v, Yb);

    k_w2<<<dim3(NOUT / 64, NPIX / 64), 256, 0, stream>>>(Yb, W2b, out);
}

// Round 3
// 643.071 us; speedup vs baseline: 2.3043x; 2.3043x over previous
//
#include <hip/hip_runtime.h>

typedef __bf16 bf16x8 __attribute__((ext_vector_type(8)));
typedef float f32x4 __attribute__((ext_vector_type(4)));

#define MFMA16(a, b, c) __builtin_amdgcn_mfma_f32_16x16x32_bf16((a), (b), (c), 0, 0, 0)

// dims
#define NB 2
#define NC 512
#define NH 96
#define NW 320
#define PH 30720      // NH*NW pixels per batch
#define NPIX 61440    // NB*PH
#define NOUT 256

__device__ __forceinline__ unsigned short f2bf(float f) {
    union { float f; unsigned u; } v; v.f = f;
    unsigned r = v.u + 0x7fffu + ((v.u >> 16) & 1u);
    return (unsigned short)(r >> 16);
}

// ---------------- weight cast f32 -> bf16 ----------------
__global__ void k_cast(const float* __restrict__ src, unsigned short* __restrict__ dst, int n) {
    int i = blockIdx.x * 256 + threadIdx.x;
    if (i < n) dst[i] = f2bf(src[i]);
}

// ---------------- transpose [b,c,hw] f32 -> [b,hw,c] bf16 ----------------
__global__ __launch_bounds__(256) void k_transpose(
        const float* __restrict__ L, const float* __restrict__ R,
        unsigned short* __restrict__ Lcl, unsigned short* __restrict__ Rcl) {
    __shared__ float t[64][65];
    int z = blockIdx.z;                 // which*2 + b
    int b = z & 1, which = z >> 1;
    const float* src = which ? R : L;
    unsigned short* dst = which ? Rcl : Lcl;
    int c0 = blockIdx.y * 64;
    int p0 = blockIdx.x * 64;
    int tx = threadIdx.x & 63, ty = threadIdx.x >> 6;
#pragma unroll
    for (int i = 0; i < 16; ++i) {
        int cl = ty + i * 4;
        t[cl][tx] = src[(b * NC + c0 + cl) * PH + p0 + tx];
    }
    __syncthreads();
#pragma unroll
    for (int i = 0; i < 16; ++i) {
        int pl = ty + i * 4;
        dst[(b * PH + p0 + pl) * NC + c0 + tx] = f2bf(t[tx][pl]);
    }
}

// ================= staged 128x128-tile GEMM (m97 structure) =================
// MODE 0: Q   = Lcl @ Wq^T        D[pix, o]   bf16
// MODE 1: K   = Rcl @ Wk^T        D[pix, o]   bf16
// MODE 2: V^T = Wv  @ Rcl^T       D[c, pix] -> Vt[b][h][c][x]  bf16 (coalesced)
// MODE 3: y   = concat(Lcl,AO) @ W1^T, BN+LeakyReLU   D[pix, o] bf16
// MODE 4: out^T = W2 @ Y^T        D[o, pix] -> f32 channels-first (coalesced)
template <int MODE>
__global__ __launch_bounds__(256) void k_gemm(
        const unsigned short* __restrict__ A0,
        const unsigned short* __restrict__ A1,
        const unsigned short* __restrict__ Bb,
        unsigned short* __restrict__ Dbf,
        float* __restrict__ Df32,
        const float* __restrict__ g, const float* __restrict__ be,
        const float* __restrict__ mu, const float* __restrict__ va) {
    constexpr int SA = (MODE == 4) ? NOUT : NC;             // A row stride (elements)
    constexpr int SB = (MODE == 3) ? 1024 : (MODE == 4) ? NOUT : NC;
    constexpr int KS = (MODE == 3) ? 32 : (MODE == 4) ? 8 : 16;  // K-steps of 32

    __shared__ unsigned short Asm[128 * 32];
    __shared__ unsigned short Bsm[128 * 32];

    const int mbase = ((MODE == 2 || MODE == 4) ? blockIdx.y : blockIdx.x) * 128;
    const int nbase = ((MODE == 2 || MODE == 4) ? blockIdx.x : blockIdx.y) * 128;

    const int lane = threadIdx.x & 63, w = threadIdx.x >> 6;
    const int lr = lane & 15, lg = lane >> 4;
    const int wr = w >> 1, wc = w & 1;

    // stage one 128x32 bf16 tile: 512 chunks of 16B; wave w owns chunks [w*128, w*128+128)
    auto stage = [&](unsigned short* lds, const unsigned short* src, int rowBase, int colOff) {
        constexpr int stride = 0;  // unused marker
        (void)stride;
#pragma unroll
        for (int j = 0; j < 2; ++j) {
            int cb = w * 128 + j * 64;           // wave-uniform chunk base
            int c = cb + lane;
            int rstride = (lds == Asm) ? SA : SB;
            const unsigned short* gp = src + (size_t)(rowBase + (c >> 2)) * rstride + colOff + (c & 3) * 8;
            __builtin_amdgcn_global_load_lds(
                (const __attribute__((address_space(1))) void*)(uintptr_t)(const void*)gp,
                (__attribute__((address_space(3))) void*)(uintptr_t)(void*)(lds + cb * 8),
                16, 0, 0);
        }
    };

    f32x4 acc[4][4] = {};

    for (int kc = 0; kc < KS; ++kc) {
        if constexpr (MODE == 3) {
            if (kc < 16) stage(Asm, A0, mbase, kc * 32);
            else         stage(Asm, A1, mbase, (kc - 16) * 32);
        } else {
            stage(Asm, A0, mbase, kc * 32);
        }
        stage(Bsm, Bb, nbase, kc * 32);
        __syncthreads();

        bf16x8 af[4], bfr[4];
#pragma unroll
        for (int i = 0; i < 4; ++i)
            af[i] = *reinterpret_cast<const bf16x8*>(Asm + (wr * 64 + i * 16 + lr) * 32 + lg * 8);
#pragma unroll
        for (int j = 0; j < 4; ++j)
            bfr[j] = *reinterpret_cast<const bf16x8*>(Bsm + (wc * 64 + j * 16 + lr) * 32 + lg * 8);
#pragma unroll
        for (int i = 0; i < 4; ++i)
#pragma unroll
            for (int j = 0; j < 4; ++j)
                acc[i][j] = MFMA16(af[i], bfr[j], acc[i][j]);
        __syncthreads();
    }

    const int lr4 = lg * 4;
    if constexpr (MODE <= 1) {
#pragma unroll
        for (int i = 0; i < 4; ++i)
#pragma unroll
            for (int j = 0; j < 4; ++j) {
                int ocol = nbase + wc * 64 + j * 16 + lr;
#pragma unroll
                for (int r = 0; r < 4; ++r) {
                    int prow = mbase + wr * 64 + i * 16 + lr4 + r;
                    Dbf[(size_t)prow * NC + ocol] = f2bf(acc[i][j][r]);
                }
            }
    } else if constexpr (MODE == 2) {
#pragma unroll
        for (int i = 0; i < 4; ++i)
#pragma unroll
            for (int j = 0; j < 4; ++j) {
                int pix = nbase + wc * 64 + j * 16 + lr;
                int b = pix / PH, ph = pix % PH;
                int hh = ph / NW, x = ph % NW;
#pragma unroll
                for (int r = 0; r < 4; ++r) {
                    int crow = mbase + wr * 64 + i * 16 + lr4 + r;
                    Dbf[((size_t)(b * NH + hh) * NC + crow) * NW + x] = f2bf(acc[i][j][r]);
                }
            }
    } else if constexpr (MODE == 3) {
#pragma unroll
        for (int j = 0; j < 4; ++j) {
            int o = nbase + wc * 64 + j * 16 + lr;
            float sc = g[o] * rsqrtf(va[o] + 1e-5f);
            float sh = be[o] - mu[o] * sc;
#pragma unroll
            for (int i = 0; i < 4; ++i)
#pragma unroll
                for (int r = 0; r < 4; ++r) {
                    int prow = mbase + wr * 64 + i * 16 + lr4 + r;
                    float y = acc[i][j][r] * sc + sh;
                    y = (y >= 0.f) ? y : 0.2f * y;
                    Dbf[(size_t)prow * NOUT + o] = f2bf(y);
                }
        }
    } else {  // MODE 4
#pragma unroll
        for (int j = 0; j < 4; ++j) {
            int pix = nbase + wc * 64 + j * 16 + lr;
            int b = pix / PH, ph = pix % PH;
#pragma unroll
            for (int i = 0; i < 4; ++i)
#pragma unroll
                for (int r = 0; r < 4; ++r) {
                    int o = mbase + wr * 64 + i * 16 + lr4 + r;
                    Df32[((size_t)b * NOUT + o) * PH + ph] = acc[i][j][r];
                }
        }
    }
}

// ---------------- attention: per (b,h), 64 q-rows per block ----------------
__global__ __launch_bounds__(256) void k_attn(
        const unsigned short* __restrict__ Q, const unsigned short* __restrict__ K,
        const unsigned short* __restrict__ Vt, unsigned short* __restrict__ O) {
    __shared__ unsigned short P[64][328];
    int qt = blockIdx.x, hh = blockIdx.y, b = blockIdx.z;
    int lane = threadIdx.x & 63, w = threadIdx.x >> 6;
    int lr = lane & 15, lg = lane >> 4;
    int rowbase = b * PH + hh * NW;     // pixel index of (b,h, x=0)
    int qrow = rowbase + qt * 64 + w * 16 + lr;

    bf16x8 qf[16];
#pragma unroll
    for (int kc = 0; kc < 16; ++kc)
        qf[kc] = *reinterpret_cast<const bf16x8*>(Q + qrow * NC + kc * 32 + lg * 8);

    f32x4 acc[20];
#pragma unroll
    for (int xt = 0; xt < 20; ++xt) acc[xt] = f32x4{0.f, 0.f, 0.f, 0.f};
#pragma unroll
    for (int xt = 0; xt < 20; ++xt) {
        int krow = rowbase + xt * 16 + lr;
#pragma unroll
        for (int kc = 0; kc < 16; ++kc) {
            bf16x8 kf = *reinterpret_cast<const bf16x8*>(K + krow * NC + kc * 32 + lg * 8);
            acc[xt] = MFMA16(qf[kc], kf, acc[xt]);
        }
    }
    // scale
#pragma unroll
    for (int xt = 0; xt < 20; ++xt)
#pragma unroll
        for (int r = 0; r < 4; ++r) acc[xt][r] *= 0.125f;
    // row max (rows lg*4+r live on the 16 lanes sharing lg)
    float m[4] = {-1e30f, -1e30f, -1e30f, -1e30f};
#pragma unroll
    for (int xt = 0; xt < 20; ++xt)
#pragma unroll
        for (int r = 0; r < 4; ++r) m[r] = fmaxf(m[r], acc[xt][r]);
#pragma unroll
    for (int mask = 1; mask < 16; mask <<= 1)
#pragma unroll
        for (int r = 0; r < 4; ++r) m[r] = fmaxf(m[r], __shfl_xor(m[r], mask));
    // exp + row sum
    float s[4] = {0.f, 0.f, 0.f, 0.f};
#pragma unroll
    for (int xt = 0; xt < 20; ++xt)
#pragma unroll
        for (int r = 0; r < 4; ++r) {
            float e = __expf(acc[xt][r] - m[r]);
            acc[xt][r] = e;
            s[r] += e;
        }
#pragma unroll
    for (int mask = 1; mask < 16; mask <<= 1)
#pragma unroll
        for (int r = 0; r < 4; ++r) s[r] += __shfl_xor(s[r], mask);
    // P -> LDS (unnormalized)
#pragma unroll
    for (int xt = 0; xt < 20; ++xt)
#pragma unroll
        for (int r = 0; r < 4; ++r)
            P[w * 16 + lg * 4 + r][xt * 16 + lr] = f2bf(acc[xt][r]);
    __syncthreads();

    bf16x8 pf[10];
#pragma unroll
    for (int kt = 0; kt < 10; ++kt)
        pf[kt] = *reinterpret_cast<const bf16x8*>(&P[w * 16 + lr][kt * 32 + lg * 8]);

    int vbase = (b * NH + hh) * NC;
#pragma unroll
    for (int ct = 0; ct < 32; ++ct) {
        f32x4 o4 = {0.f, 0.f, 0.f, 0.f};
#pragma unroll
        for (int kt = 0; kt < 10; ++kt) {
            bf16x8 vf = *reinterpret_cast<const bf16x8*>(Vt + (vbase + ct * 16 + lr) * NW + kt * 32 + lg * 8);
            o4 = MFMA16(pf[kt], vf, o4);
        }
#pragma unroll
        for (int r = 0; r < 4; ++r) {
            int prow = rowbase + qt * 64 + w * 16 + lg * 4 + r;
            O[prow * NC + ct * 16 + lr] = f2bf(o4[r] / s[r]);
        }
    }
}

extern "C" void kernel_launch(void* const* d_in, const int* in_sizes, int n_in,
                              void* d_out, int out_size, void* d_ws, size_t ws_size,
                              hipStream_t stream) {
    const float* left  = (const float*)d_in[0];
    const float* right = (const float*)d_in[1];
    const float* wq = (const float*)d_in[2];
    const float* wk = (const float*)d_in[3];
    const float* wv = (const float*)d_in[4];
    const float* w1 = (const float*)d_in[5];
    const float* bn_g = (const float*)d_in[6];
    const float* bn_b = (const float*)d_in[7];
    const float* bn_m = (const float*)d_in[8];
    const float* bn_v = (const float*)d_in[9];
    const float* w2 = (const float*)d_in[10];
    float* out = (float*)d_out;

    size_t off = 0;
    auto alloc = [&](size_t bytes) -> void* {
        void* p = (char*)d_ws + off;
        off += (bytes + 255) & ~(size_t)255;
        return p;
    };
    const size_t clb = (size_t)NPIX * NC * 2;        // 62.9 MB
    unsigned short* Lcl = (unsigned short*)alloc(clb);
    unsigned short* Rcl = (unsigned short*)alloc(clb);
    unsigned short* Qb  = (unsigned short*)alloc(clb);
    unsigned short* Kb  = (unsigned short*)alloc(clb);
    unsigned short* Vt  = (unsigned short*)alloc(clb);
    unsigned short* Wqb = (unsigned short*)alloc((size_t)NC * NC * 2);
    unsigned short* Wkb = (unsigned short*)alloc((size_t)NC * NC * 2);
    unsigned short* Wvb = (unsigned short*)alloc((size_t)NC * NC * 2);
    unsigned short* W1b = (unsigned short*)alloc((size_t)NOUT * 1024 * 2);
    unsigned short* W2b = (unsigned short*)alloc((size_t)NOUT * NOUT * 2);
    unsigned short* AO = Rcl;   // attention output aliases Rcl (dead after projections)
    unsigned short* Yb = Qb;    // y aliases Qb (dead after attention)

    k_cast<<<dim3((NC * NC + 255) / 256), 256, 0, stream>>>(wq, Wqb, NC * NC);
    k_cast<<<dim3((NC * NC + 255) / 256), 256, 0, stream>>>(wk, Wkb, NC * NC);
    k_cast<<<dim3((NC * NC + 255) / 256), 256, 0, stream>>>(wv, Wvb, NC * NC);
    k_cast<<<dim3((NOUT * 1024 + 255) / 256), 256, 0, stream>>>(w1, W1b, NOUT * 1024);
    k_cast<<<dim3((NOUT * NOUT + 255) / 256), 256, 0, stream>>>(w2, W2b, NOUT * NOUT);

    k_transpose<<<dim3(PH / 64, NC / 64, 4), 256, 0, stream>>>(left, right, Lcl, Rcl);

    // Q: [61440,512] = Lcl @ Wq^T   (grid: x = pix tiles, y = o tiles)
    k_gemm<0><<<dim3(NPIX / 128, NC / 128), 256, 0, stream>>>(Lcl, nullptr, Wqb, Qb, nullptr, nullptr, nullptr, nullptr, nullptr);
    // K: Rcl @ Wk^T
    k_gemm<1><<<dim3(NPIX / 128, NC / 128), 256, 0, stream>>>(Rcl, nullptr, Wkb, Kb, nullptr, nullptr, nullptr, nullptr, nullptr);
    // V^T: Wv @ Rcl^T  (grid: x = pix tiles (N), y = c tiles (M))
    k_gemm<2><<<dim3(NPIX / 128, NC / 128), 256, 0, stream>>>(Wvb, nullptr, Rcl, Vt, nullptr, nullptr, nullptr, nullptr, nullptr);

    k_attn<<<dim3(NW / 64, NH, NB), 256, 0, stream>>>(Qb, Kb, Vt, AO);

    // w1 + BN + LeakyReLU: concat K
    k_gemm<3><<<dim3(NPIX / 128, NOUT / 128), 256, 0, stream>>>(Lcl, AO, W1b, Yb, nullptr, bn_g, bn_b, bn_m, bn_v);

    // w2 transposed-compute, f32 channels-first out
    k_gemm<4><<<dim3(NPIX / 128, NOUT / 128), 256, 0, stream>>>(W2b, nullptr, Yb, nullptr, out, nullptr, nullptr, nullptr, nullptr);
}

// Round 4
// 431.204 us; speedup vs baseline: 3.4365x; 1.4913x over previous
//
#include <hip/hip_runtime.h>

typedef __bf16 bf16x8 __attribute__((ext_vector_type(8)));
typedef float f32x4 __attribute__((ext_vector_type(4)));

#define MFMA16(a, b, c) __builtin_amdgcn_mfma_f32_16x16x32_bf16((a), (b), (c), 0, 0, 0)
#define GLOAD_LDS(gp, lp) __builtin_amdgcn_global_load_lds( \
    (const __attribute__((address_space(1))) void*)(uintptr_t)(const void*)(gp), \
    (__attribute__((address_space(3))) void*)(uintptr_t)(void*)(lp), 16, 0, 0)

// dims
#define NB 2
#define NC 512
#define NH 96
#define NW 320
#define PH 30720      // NH*NW pixels per batch
#define NPIX 61440    // NB*PH
#define NOUT 256

__device__ __forceinline__ unsigned short f2bf(float f) {
    union { float f; unsigned u; } v; v.f = f;
    unsigned r = v.u + 0x7fffu + ((v.u >> 16) & 1u);
    return (unsigned short)(r >> 16);
}

// ---------------- weight cast f32 -> bf16 ----------------
__global__ void k_cast(const float* __restrict__ src, unsigned short* __restrict__ dst, int n) {
    int i = blockIdx.x * 256 + threadIdx.x;
    if (i < n) dst[i] = f2bf(src[i]);
}

// ---------------- transpose [b,c,hw] f32 -> [b,hw,c] bf16 ----------------
__global__ __launch_bounds__(256) void k_transpose(
        const float* __restrict__ L, const float* __restrict__ R,
        unsigned short* __restrict__ Lcl, unsigned short* __restrict__ Rcl) {
    __shared__ float t[64][65];
    int z = blockIdx.z;                 // which*2 + b
    int b = z & 1, which = z >> 1;
    const float* src = which ? R : L;
    unsigned short* dst = which ? Rcl : Lcl;
    int c0 = blockIdx.y * 64;
    int p0 = blockIdx.x * 64;
    int tx = threadIdx.x & 63, ty = threadIdx.x >> 6;
#pragma unroll
    for (int i = 0; i < 16; ++i) {
        int cl = ty + i * 4;
        t[cl][tx] = src[(b * NC + c0 + cl) * PH + p0 + tx];
    }
    __syncthreads();
#pragma unroll
    for (int i = 0; i < 16; ++i) {
        int pl = ty + i * 4;
        dst[(b * PH + p0 + pl) * NC + c0 + tx] = f2bf(t[tx][pl]);
    }
}

// ================= staged 128x128-tile GEMM (m97 structure) =================
// MODE 0: Q   = Lcl @ Wq^T        D[pix, o]   bf16
// MODE 1: K   = Rcl @ Wk^T        D[pix, o]   bf16
// MODE 2: V^T = Wv  @ Rcl^T       D[c, pix] -> Vt[b][h][c][x]  bf16 (coalesced)
// MODE 3: y   = concat(Lcl,AO) @ W1^T, BN+LeakyReLU   D[pix, o] bf16
// MODE 4: out^T = W2 @ Y^T        D[o, pix] -> f32 channels-first (coalesced)
// 1D grid, XCD-chunked swizzle: same pixel-panel's o-tiles adjacent on one XCD.
template <int MODE>
__global__ __launch_bounds__(256) void k_gemm(
        const unsigned short* __restrict__ A0,
        const unsigned short* __restrict__ A1,
        const unsigned short* __restrict__ Bb,
        unsigned short* __restrict__ Dbf,
        float* __restrict__ Df32,
        const float* __restrict__ g, const float* __restrict__ be,
        const float* __restrict__ mu, const float* __restrict__ va) {
    constexpr int SA = (MODE == 4) ? NOUT : NC;             // A row stride (elements)
    constexpr int SB = (MODE == 3) ? 1024 : (MODE == 4) ? NOUT : NC;
    constexpr int KS = (MODE == 3) ? 32 : (MODE == 4) ? 8 : 16;  // K-steps of 32
    constexpr int NTO = (MODE <= 2) ? 4 : 2;                // non-pixel tile count
    constexpr int TOT = 480 * NTO;

    __shared__ unsigned short Asm[128 * 32];
    __shared__ unsigned short Bsm[128 * 32];

    int pphys = blockIdx.x;
    int lgc = (pphys & 7) * (TOT / 8) + (pphys >> 3);
    int pixt = lgc / NTO, ot = lgc % NTO;
    const int mbase = ((MODE == 2 || MODE == 4) ? ot : pixt) * 128;
    const int nbase = ((MODE == 2 || MODE == 4) ? pixt : ot) * 128;

    const int lane = threadIdx.x & 63, w = threadIdx.x >> 6;
    const int lr = lane & 15, lg = lane >> 4;
    const int wr = w >> 1, wc = w & 1;

    // stage one 128x32 bf16 tile: 512 chunks of 16B; wave w owns chunks [w*128, w*128+128)
    auto stage = [&](unsigned short* lds, const unsigned short* src, int rowBase, int colOff) {
#pragma unroll
        for (int j = 0; j < 2; ++j) {
            int cb = w * 128 + j * 64;           // wave-uniform chunk base
            int c = cb + lane;
            int rstride = (lds == Asm) ? SA : SB;
            const unsigned short* gp = src + (size_t)(rowBase + (c >> 2)) * rstride + colOff + (c & 3) * 8;
            GLOAD_LDS(gp, lds + cb * 8);
        }
    };

    f32x4 acc[4][4] = {};

    for (int kc = 0; kc < KS; ++kc) {
        if constexpr (MODE == 3) {
            if (kc < 16) stage(Asm, A0, mbase, kc * 32);
            else         stage(Asm, A1, mbase, (kc - 16) * 32);
        } else {
            stage(Asm, A0, mbase, kc * 32);
        }
        stage(Bsm, Bb, nbase, kc * 32);
        __syncthreads();

        bf16x8 af[4], bfr[4];
#pragma unroll
        for (int i = 0; i < 4; ++i)
            af[i] = *reinterpret_cast<const bf16x8*>(Asm + (wr * 64 + i * 16 + lr) * 32 + lg * 8);
#pragma unroll
        for (int j = 0; j < 4; ++j)
            bfr[j] = *reinterpret_cast<const bf16x8*>(Bsm + (wc * 64 + j * 16 + lr) * 32 + lg * 8);
#pragma unroll
        for (int i = 0; i < 4; ++i)
#pragma unroll
            for (int j = 0; j < 4; ++j)
                acc[i][j] = MFMA16(af[i], bfr[j], acc[i][j]);
        __syncthreads();
    }

    const int lr4 = lg * 4;
    if constexpr (MODE <= 1) {
#pragma unroll
        for (int i = 0; i < 4; ++i)
#pragma unroll
            for (int j = 0; j < 4; ++j) {
                int ocol = nbase + wc * 64 + j * 16 + lr;
#pragma unroll
                for (int r = 0; r < 4; ++r) {
                    int prow = mbase + wr * 64 + i * 16 + lr4 + r;
                    Dbf[(size_t)prow * NC + ocol] = f2bf(acc[i][j][r]);
                }
            }
    } else if constexpr (MODE == 2) {
#pragma unroll
        for (int i = 0; i < 4; ++i)
#pragma unroll
            for (int j = 0; j < 4; ++j) {
                int pix = nbase + wc * 64 + j * 16 + lr;
                int b = pix / PH, ph = pix % PH;
                int hh = ph / NW, x = ph % NW;
#pragma unroll
                for (int r = 0; r < 4; ++r) {
                    int crow = mbase + wr * 64 + i * 16 + lr4 + r;
                    Dbf[((size_t)(b * NH + hh) * NC + crow) * NW + x] = f2bf(acc[i][j][r]);
                }
            }
    } else if constexpr (MODE == 3) {
#pragma unroll
        for (int j = 0; j < 4; ++j) {
            int o = nbase + wc * 64 + j * 16 + lr;
            float sc = g[o] * rsqrtf(va[o] + 1e-5f);
            float sh = be[o] - mu[o] * sc;
#pragma unroll
            for (int i = 0; i < 4; ++i)
#pragma unroll
                for (int r = 0; r < 4; ++r) {
                    int prow = mbase + wr * 64 + i * 16 + lr4 + r;
                    float y = acc[i][j][r] * sc + sh;
                    y = (y >= 0.f) ? y : 0.2f * y;
                    Dbf[(size_t)prow * NOUT + o] = f2bf(y);
                }
        }
    } else {  // MODE 4
#pragma unroll
        for (int j = 0; j < 4; ++j) {
            int pix = nbase + wc * 64 + j * 16 + lr;
            int b = pix / PH, ph = pix % PH;
#pragma unroll
            for (int i = 0; i < 4; ++i)
#pragma unroll
                for (int r = 0; r < 4; ++r) {
                    int o = mbase + wr * 64 + i * 16 + lr4 + r;
                    Df32[((size_t)b * NOUT + o) * PH + ph] = acc[i][j][r];
                }
        }
    }
}

// ---------------- attention: per (b,h), 64 q-rows per block, LDS-staged K/V ----------------
// grid 960 1D, XCD-chunked swizzle: the 5 q-tile blocks of one head colocate on one XCD.
__global__ __launch_bounds__(256, 2) void k_attn(
        const unsigned short* __restrict__ Q, const unsigned short* __restrict__ K,
        const unsigned short* __restrict__ Vt, unsigned short* __restrict__ O) {
    __shared__ unsigned short P[64][328];
    __shared__ unsigned short KV[32 * 512];   // K-tile [32][512] (swizzled) / V-tile [512c][32x]

    int pphys = blockIdx.x;
    int l = (pphys & 7) * 120 + (pphys >> 3);
    int head = l / 5, qt = l % 5;
    int b = head / NH, hh = head % NH;
    int lane = threadIdx.x & 63, w = threadIdx.x >> 6;
    int lr = lane & 15, lg = lane >> 4;
    int rowbase = b * PH + hh * NW;     // pixel index of (b,h, x=0)
    int qrow = rowbase + qt * 64 + w * 16 + lr;

    bf16x8 qf[16];
#pragma unroll
    for (int kc = 0; kc < 16; ++kc)
        qf[kc] = *reinterpret_cast<const bf16x8*>(Q + (size_t)qrow * NC + kc * 32 + lg * 8);

    f32x4 acc[20];
#pragma unroll
    for (int xt = 0; xt < 20; ++xt) acc[xt] = f32x4{0.f, 0.f, 0.f, 0.f};

    // ---- QK^T: 10 staged K-tiles of 32 rows ----
#pragma unroll
    for (int s = 0; s < 10; ++s) {
        // stage: wave w issue j stages row r = w*8+j (1024 B = 64 lanes x 16B).
        // pre-swizzled source: LDS slot p holds global slot p ^ (r&7).
#pragma unroll
        for (int j = 0; j < 8; ++j) {
            int r = w * 8 + j;
            const unsigned short* gp = K + (size_t)(rowbase + s * 32 + r) * NC + ((lane ^ (r & 7)) * 8);
            GLOAD_LDS(gp, KV + r * 512);
        }
        __syncthreads();
#pragma unroll
        for (int x2 = 0; x2 < 2; ++x2) {
            int rrow = x2 * 16 + lr;
            int rsw = lr & 7;
#pragma unroll
            for (int kc = 0; kc < 16; ++kc) {
                bf16x8 kf = *reinterpret_cast<const bf16x8*>(KV + rrow * 512 + (((kc * 4 + lg) ^ rsw) * 8));
                acc[s * 2 + x2] = MFMA16(qf[kc], kf, acc[s * 2 + x2]);
            }
        }
        __syncthreads();
    }

    // ---- softmax (rows lg*4+r live on the 16 lanes sharing lg) ----
#pragma unroll
    for (int xt = 0; xt < 20; ++xt)
#pragma unroll
        for (int r = 0; r < 4; ++r) acc[xt][r] *= 0.125f;
    float m[4] = {-1e30f, -1e30f, -1e30f, -1e30f};
#pragma unroll
    for (int xt = 0; xt < 20; ++xt)
#pragma unroll
        for (int r = 0; r < 4; ++r) m[r] = fmaxf(m[r], acc[xt][r]);
#pragma unroll
    for (int mask = 1; mask < 16; mask <<= 1)
#pragma unroll
        for (int r = 0; r < 4; ++r) m[r] = fmaxf(m[r], __shfl_xor(m[r], mask));
    float s4[4] = {0.f, 0.f, 0.f, 0.f};
#pragma unroll
    for (int xt = 0; xt < 20; ++xt)
#pragma unroll
        for (int r = 0; r < 4; ++r) {
            float e = __expf(acc[xt][r] - m[r]);
            acc[xt][r] = e;
            s4[r] += e;
        }
#pragma unroll
    for (int mask = 1; mask < 16; mask <<= 1)
#pragma unroll
        for (int r = 0; r < 4; ++r) s4[r] += __shfl_xor(s4[r], mask);
    // P -> LDS (unnormalized)
#pragma unroll
    for (int xt = 0; xt < 20; ++xt)
#pragma unroll
        for (int r = 0; r < 4; ++r)
            P[w * 16 + lg * 4 + r][xt * 16 + lr] = f2bf(acc[xt][r]);
    __syncthreads();

    // ---- PV: 10 staged V-tiles [512 c][32 x]; persistent O accumulator ----
    f32x4 oacc[32];
#pragma unroll
    for (int ct = 0; ct < 32; ++ct) oacc[ct] = f32x4{0.f, 0.f, 0.f, 0.f};

    int vbase = (b * NH + hh) * NC;
    for (int s = 0; s < 10; ++s) {
#pragma unroll
        for (int j = 0; j < 8; ++j) {
            int c = (w * 8 + j) * 16 + (lane >> 2);          // 16 c-rows per issue
            const unsigned short* gp = Vt + (size_t)(vbase + c) * NW + s * 32 + (lane & 3) * 8;
            GLOAD_LDS(gp, KV + (w * 8 + j) * 512);
        }
        __syncthreads();
        bf16x8 pf = *reinterpret_cast<const bf16x8*>(&P[w * 16 + lr][s * 32 + lg * 8]);
#pragma unroll
        for (int ct = 0; ct < 32; ++ct) {
            bf16x8 vf = *reinterpret_cast<const bf16x8*>(KV + (ct * 16 + lr) * 32 + lg * 8);
            oacc[ct] = MFMA16(pf, vf, oacc[ct]);
        }
        __syncthreads();
    }

#pragma unroll
    for (int ct = 0; ct < 32; ++ct)
#pragma unroll
        for (int r = 0; r < 4; ++r) {
            int prow = rowbase + qt * 64 + w * 16 + lg * 4 + r;
            O[(size_t)prow * NC + ct * 16 + lr] = f2bf(oacc[ct][r] / s4[r]);
        }
}

extern "C" void kernel_launch(void* const* d_in, const int* in_sizes, int n_in,
                              void* d_out, int out_size, void* d_ws, size_t ws_size,
                              hipStream_t stream) {
    const float* left  = (const float*)d_in[0];
    const float* right = (const float*)d_in[1];
    const float* wq = (const float*)d_in[2];
    const float* wk = (const float*)d_in[3];
    const float* wv = (const float*)d_in[4];
    const float* w1 = (const float*)d_in[5];
    const float* bn_g = (const float*)d_in[6];
    const float* bn_b = (const float*)d_in[7];
    const float* bn_m = (const float*)d_in[8];
    const float* bn_v = (const float*)d_in[9];
    const float* w2 = (const float*)d_in[10];
    float* out = (float*)d_out;

    size_t off = 0;
    auto alloc = [&](size_t bytes) -> void* {
        void* p = (char*)d_ws + off;
        off += (bytes + 255) & ~(size_t)255;
        return p;
    };
    const size_t clb = (size_t)NPIX * NC * 2;        // 62.9 MB
    unsigned short* Lcl = (unsigned short*)alloc(clb);
    unsigned short* Rcl = (unsigned short*)alloc(clb);
    unsigned short* Qb  = (unsigned short*)alloc(clb);
    unsigned short* Kb  = (unsigned short*)alloc(clb);
    unsigned short* Vt  = (unsigned short*)alloc(clb);
    unsigned short* Wqb = (unsigned short*)alloc((size_t)NC * NC * 2);
    unsigned short* Wkb = (unsigned short*)alloc((size_t)NC * NC * 2);
    unsigned short* Wvb = (unsigned short*)alloc((size_t)NC * NC * 2);
    unsigned short* W1b = (unsigned short*)alloc((size_t)NOUT * 1024 * 2);
    unsigned short* W2b = (unsigned short*)alloc((size_t)NOUT * NOUT * 2);
    unsigned short* AO = Rcl;   // attention output aliases Rcl (dead after projections)
    unsigned short* Yb = Qb;    // y aliases Qb (dead after attention)

    k_cast<<<dim3((NC * NC + 255) / 256), 256, 0, stream>>>(wq, Wqb, NC * NC);
    k_cast<<<dim3((NC * NC + 255) / 256), 256, 0, stream>>>(wk, Wkb, NC * NC);
    k_cast<<<dim3((NC * NC + 255) / 256), 256, 0, stream>>>(wv, Wvb, NC * NC);
    k_cast<<<dim3((NOUT * 1024 + 255) / 256), 256, 0, stream>>>(w1, W1b, NOUT * 1024);
    k_cast<<<dim3((NOUT * NOUT + 255) / 256), 256, 0, stream>>>(w2, W2b, NOUT * NOUT);

    k_transpose<<<dim3(PH / 64, NC / 64, 4), 256, 0, stream>>>(left, right, Lcl, Rcl);

    // Q: [61440,512] = Lcl @ Wq^T
    k_gemm<0><<<dim3(1920), 256, 0, stream>>>(Lcl, nullptr, Wqb, Qb, nullptr, nullptr, nullptr, nullptr, nullptr);
    // K: Rcl @ Wk^T
    k_gemm<1><<<dim3(1920), 256, 0, stream>>>(Rcl, nullptr, Wkb, Kb, nullptr, nullptr, nullptr, nullptr, nullptr);
    // V^T: Wv @ Rcl^T
    k_gemm<2><<<dim3(1920), 256, 0, stream>>>(Wvb, nullptr, Rcl, Vt, nullptr, nullptr, nullptr, nullptr, nullptr);

    k_attn<<<dim3(960), 256, 0, stream>>>(Qb, Kb, Vt, AO);

    // w1 + BN + LeakyReLU: concat K
    k_gemm<3><<<dim3(960), 256, 0, stream>>>(Lcl, AO, W1b, Yb, nullptr, bn_g, bn_b, bn_m, bn_v);

    // w2 transposed-compute, f32 channels-first out
    k_gemm<4><<<dim3(960), 256, 0, stream>>>(W2b, nullptr, Yb, nullptr, out, nullptr, nullptr, nullptr, nullptr);
}

// Round 5
// 429.434 us; speedup vs baseline: 3.4507x; 1.0041x over previous
//
#include <hip/hip_runtime.h>

typedef __bf16 bf16x8 __attribute__((ext_vector_type(8)));
typedef float f32x4 __attribute__((ext_vector_type(4)));

#define MFMA16(a, b, c) __builtin_amdgcn_mfma_f32_16x16x32_bf16((a), (b), (c), 0, 0, 0)
#define GLOAD_LDS(gp, lp) __builtin_amdgcn_global_load_lds( \
    (const __attribute__((address_space(1))) void*)(uintptr_t)(const void*)(gp), \
    (__attribute__((address_space(3))) void*)(uintptr_t)(void*)(lp), 16, 0, 0)

// dims
#define NB 2
#define NC 512
#define NH 96
#define NW 320
#define PH 30720      // NH*NW pixels per batch
#define NPIX 61440    // NB*PH
#define NOUT 256

__device__ __forceinline__ unsigned short f2bf(float f) {
    union { float f; unsigned u; } v; v.f = f;
    unsigned r = v.u + 0x7fffu + ((v.u >> 16) & 1u);
    return (unsigned short)(r >> 16);
}

// ---------------- weight cast f32 -> bf16 ----------------
__global__ void k_cast(const float* __restrict__ src, unsigned short* __restrict__ dst, int n) {
    int i = blockIdx.x * 256 + threadIdx.x;
    if (i < n) dst[i] = f2bf(src[i]);
}

// ---------------- transpose [b,c,hw] f32 -> [b,hw,c] bf16 ----------------
__global__ __launch_bounds__(256) void k_transpose(
        const float* __restrict__ L, const float* __restrict__ R,
        unsigned short* __restrict__ Lcl, unsigned short* __restrict__ Rcl) {
    __shared__ float t[64][65];
    int z = blockIdx.z;                 // which*2 + b
    int b = z & 1, which = z >> 1;
    const float* src = which ? R : L;
    unsigned short* dst = which ? Rcl : Lcl;
    int c0 = blockIdx.y * 64;
    int p0 = blockIdx.x * 64;
    int tx = threadIdx.x & 63, ty = threadIdx.x >> 6;
#pragma unroll
    for (int i = 0; i < 16; ++i) {
        int cl = ty + i * 4;
        t[cl][tx] = src[(b * NC + c0 + cl) * PH + p0 + tx];
    }
    __syncthreads();
#pragma unroll
    for (int i = 0; i < 16; ++i) {
        int pl = ty + i * 4;
        dst[(b * PH + p0 + pl) * NC + c0 + tx] = f2bf(t[tx][pl]);
    }
}

// ================= staged 128x128-tile GEMM (m97 structure) =================
// MODE 0: Q   = Lcl @ Wq^T        D[pix, o]   bf16
// MODE 1: K   = Rcl @ Wk^T        D[pix, o]   bf16
// MODE 2: V^T = Wv  @ Rcl^T       D[c, pix] -> Vt[b][h][c][x]  bf16 (coalesced)
// MODE 3: y   = concat(Lcl,AO) @ W1^T, BN+LeakyReLU   D[pix, o] bf16
// MODE 4: out^T = W2 @ Y^T        D[o, pix] -> f32 channels-first (coalesced)
// 1D grid, XCD-chunked swizzle: same pixel-panel's o-tiles adjacent on one XCD.
template <int MODE>
__global__ __launch_bounds__(256) void k_gemm(
        const unsigned short* __restrict__ A0,
        const unsigned short* __restrict__ A1,
        const unsigned short* __restrict__ Bb,
        unsigned short* __restrict__ Dbf,
        float* __restrict__ Df32,
        const float* __restrict__ g, const float* __restrict__ be,
        const float* __restrict__ mu, const float* __restrict__ va) {
    constexpr int SA = (MODE == 4) ? NOUT : NC;             // A row stride (elements)
    constexpr int SB = (MODE == 3) ? 1024 : (MODE == 4) ? NOUT : NC;
    constexpr int KS = (MODE == 3) ? 32 : (MODE == 4) ? 8 : 16;  // K-steps of 32
    constexpr int NTO = (MODE <= 2) ? 4 : 2;                // non-pixel tile count
    constexpr int TOT = 480 * NTO;

    __shared__ unsigned short Asm[128 * 32];
    __shared__ unsigned short Bsm[128 * 32];

    int pphys = blockIdx.x;
    int lgc = (pphys & 7) * (TOT / 8) + (pphys >> 3);
    int pixt = lgc / NTO, ot = lgc % NTO;
    const int mbase = ((MODE == 2 || MODE == 4) ? ot : pixt) * 128;
    const int nbase = ((MODE == 2 || MODE == 4) ? pixt : ot) * 128;

    const int lane = threadIdx.x & 63, w = threadIdx.x >> 6;
    const int lr = lane & 15, lg = lane >> 4;
    const int wr = w >> 1, wc = w & 1;

    // stage one 128x32 bf16 tile: 512 chunks of 16B; wave w owns chunks [w*128, w*128+128)
    auto stage = [&](unsigned short* lds, const unsigned short* src, int rowBase, int colOff) {
#pragma unroll
        for (int j = 0; j < 2; ++j) {
            int cb = w * 128 + j * 64;           // wave-uniform chunk base
            int c = cb + lane;
            int rstride = (lds == Asm) ? SA : SB;
            const unsigned short* gp = src + (size_t)(rowBase + (c >> 2)) * rstride + colOff + (c & 3) * 8;
            GLOAD_LDS(gp, lds + cb * 8);
        }
    };

    f32x4 acc[4][4] = {};

    for (int kc = 0; kc < KS; ++kc) {
        if constexpr (MODE == 3) {
            if (kc < 16) stage(Asm, A0, mbase, kc * 32);
            else         stage(Asm, A1, mbase, (kc - 16) * 32);
        } else {
            stage(Asm, A0, mbase, kc * 32);
        }
        stage(Bsm, Bb, nbase, kc * 32);
        __syncthreads();

        bf16x8 af[4], bfr[4];
#pragma unroll
        for (int i = 0; i < 4; ++i)
            af[i] = *reinterpret_cast<const bf16x8*>(Asm + (wr * 64 + i * 16 + lr) * 32 + lg * 8);
#pragma unroll
        for (int j = 0; j < 4; ++j)
            bfr[j] = *reinterpret_cast<const bf16x8*>(Bsm + (wc * 64 + j * 16 + lr) * 32 + lg * 8);
#pragma unroll
        for (int i = 0; i < 4; ++i)
#pragma unroll
            for (int j = 0; j < 4; ++j)
                acc[i][j] = MFMA16(af[i], bfr[j], acc[i][j]);
        __syncthreads();
    }

    const int lr4 = lg * 4;
    if constexpr (MODE <= 1) {
#pragma unroll
        for (int i = 0; i < 4; ++i)
#pragma unroll
            for (int j = 0; j < 4; ++j) {
                int ocol = nbase + wc * 64 + j * 16 + lr;
#pragma unroll
                for (int r = 0; r < 4; ++r) {
                    int prow = mbase + wr * 64 + i * 16 + lr4 + r;
                    Dbf[(size_t)prow * NC + ocol] = f2bf(acc[i][j][r]);
                }
            }
    } else if constexpr (MODE == 2) {
#pragma unroll
        for (int i = 0; i < 4; ++i)
#pragma unroll
            for (int j = 0; j < 4; ++j) {
                int pix = nbase + wc * 64 + j * 16 + lr;
                int b = pix / PH, ph = pix % PH;
                int hh = ph / NW, x = ph % NW;
#pragma unroll
                for (int r = 0; r < 4; ++r) {
                    int crow = mbase + wr * 64 + i * 16 + lr4 + r;
                    Dbf[((size_t)(b * NH + hh) * NC + crow) * NW + x] = f2bf(acc[i][j][r]);
                }
            }
    } else if constexpr (MODE == 3) {
#pragma unroll
        for (int j = 0; j < 4; ++j) {
            int o = nbase + wc * 64 + j * 16 + lr;
            float sc = g[o] * rsqrtf(va[o] + 1e-5f);
            float sh = be[o] - mu[o] * sc;
#pragma unroll
            for (int i = 0; i < 4; ++i)
#pragma unroll
                for (int r = 0; r < 4; ++r) {
                    int prow = mbase + wr * 64 + i * 16 + lr4 + r;
                    float y = acc[i][j][r] * sc + sh;
                    y = (y >= 0.f) ? y : 0.2f * y;
                    Dbf[(size_t)prow * NOUT + o] = f2bf(y);
                }
        }
    } else {  // MODE 4
#pragma unroll
        for (int j = 0; j < 4; ++j) {
            int pix = nbase + wc * 64 + j * 16 + lr;
            int b = pix / PH, ph = pix % PH;
#pragma unroll
            for (int i = 0; i < 4; ++i)
#pragma unroll
                for (int r = 0; r < 4; ++r) {
                    int o = mbase + wr * 64 + i * 16 + lr4 + r;
                    Df32[((size_t)b * NOUT + o) * PH + ph] = acc[i][j][r];
                }
        }
    }
}

// ---------------- attention: per (b,h), 64 q-rows per block, LDS-staged K/V ----------------
// grid 960 1D, XCD-chunked swizzle: the 5 q-tile blocks of one head colocate on one XCD.
// V-tile x-quad slots XOR-swizzled by c-row so PV ds_read_b128 is bank-conflict-free:
//   LDS[cgrp][cin][xq] holds global x-quad (xq ^ ((cin>>1)&3))  [pre-swizzled source, linear dest]
__global__ __launch_bounds__(256, 2) void k_attn(
        const unsigned short* __restrict__ Q, const unsigned short* __restrict__ K,
        const unsigned short* __restrict__ Vt, unsigned short* __restrict__ O) {
    __shared__ unsigned short P[64][328];
    __shared__ unsigned short KV[32 * 512];   // K-tile [32][512] (swizzled) / V-tile [512c][32x] (slot-swizzled)

    int pphys = blockIdx.x;
    int l = (pphys & 7) * 120 + (pphys >> 3);
    int head = l / 5, qt = l % 5;
    int b = head / NH, hh = head % NH;
    int lane = threadIdx.x & 63, w = threadIdx.x >> 6;
    int lr = lane & 15, lg = lane >> 4;
    int rowbase = b * PH + hh * NW;     // pixel index of (b,h, x=0)
    int qrow = rowbase + qt * 64 + w * 16 + lr;

    bf16x8 qf[16];
#pragma unroll
    for (int kc = 0; kc < 16; ++kc)
        qf[kc] = *reinterpret_cast<const bf16x8*>(Q + (size_t)qrow * NC + kc * 32 + lg * 8);

    f32x4 acc[20];
#pragma unroll
    for (int xt = 0; xt < 20; ++xt) acc[xt] = f32x4{0.f, 0.f, 0.f, 0.f};

    // ---- QK^T: 10 staged K-tiles of 32 rows ----
#pragma unroll
    for (int s = 0; s < 10; ++s) {
        // stage: wave w issue j stages row r = w*8+j (1024 B = 64 lanes x 16B).
        // pre-swizzled source: LDS slot p holds global slot p ^ (r&7).
#pragma unroll
        for (int j = 0; j < 8; ++j) {
            int r = w * 8 + j;
            const unsigned short* gp = K + (size_t)(rowbase + s * 32 + r) * NC + ((lane ^ (r & 7)) * 8);
            GLOAD_LDS(gp, KV + r * 512);
        }
        __syncthreads();
#pragma unroll
        for (int x2 = 0; x2 < 2; ++x2) {
            int rrow = x2 * 16 + lr;
            int rsw = lr & 7;
#pragma unroll
            for (int kc = 0; kc < 16; ++kc) {
                bf16x8 kf = *reinterpret_cast<const bf16x8*>(KV + rrow * 512 + (((kc * 4 + lg) ^ rsw) * 8));
                acc[s * 2 + x2] = MFMA16(qf[kc], kf, acc[s * 2 + x2]);
            }
        }
        __syncthreads();
    }

    // ---- softmax (rows lg*4+r live on the 16 lanes sharing lg) ----
#pragma unroll
    for (int xt = 0; xt < 20; ++xt)
#pragma unroll
        for (int r = 0; r < 4; ++r) acc[xt][r] *= 0.125f;
    float m[4] = {-1e30f, -1e30f, -1e30f, -1e30f};
#pragma unroll
    for (int xt = 0; xt < 20; ++xt)
#pragma unroll
        for (int r = 0; r < 4; ++r) m[r] = fmaxf(m[r], acc[xt][r]);
#pragma unroll
    for (int mask = 1; mask < 16; mask <<= 1)
#pragma unroll
        for (int r = 0; r < 4; ++r) m[r] = fmaxf(m[r], __shfl_xor(m[r], mask));
    float s4[4] = {0.f, 0.f, 0.f, 0.f};
#pragma unroll
    for (int xt = 0; xt < 20; ++xt)
#pragma unroll
        for (int r = 0; r < 4; ++r) {
            float e = __expf(acc[xt][r] - m[r]);
            acc[xt][r] = e;
            s4[r] += e;
        }
#pragma unroll
    for (int mask = 1; mask < 16; mask <<= 1)
#pragma unroll
        for (int r = 0; r < 4; ++r) s4[r] += __shfl_xor(s4[r], mask);
    // P -> LDS (unnormalized)
#pragma unroll
    for (int xt = 0; xt < 20; ++xt)
#pragma unroll
        for (int r = 0; r < 4; ++r)
            P[w * 16 + lg * 4 + r][xt * 16 + lr] = f2bf(acc[xt][r]);
    __syncthreads();

    // ---- PV: 10 staged V-tiles [512 c][32 x], slot-swizzled; persistent O accumulator ----
    f32x4 oacc[32];
#pragma unroll
    for (int ct = 0; ct < 32; ++ct) oacc[ct] = f32x4{0.f, 0.f, 0.f, 0.f};

    int vbase = (b * NH + hh) * NC;
    for (int s = 0; s < 10; ++s) {
#pragma unroll
        for (int j = 0; j < 8; ++j) {
            int c = (w * 8 + j) * 16 + (lane >> 2);          // 16 c-rows per issue
            int qg = (lane & 3) ^ ((lane >> 3) & 3);         // global x-quad for this LDS slot
            const unsigned short* gp = Vt + (size_t)(vbase + c) * NW + s * 32 + qg * 8;
            GLOAD_LDS(gp, KV + (w * 8 + j) * 512);
        }
        __syncthreads();
        bf16x8 pf = *reinterpret_cast<const bf16x8*>(&P[w * 16 + lr][s * 32 + lg * 8]);
#pragma unroll
        for (int ct = 0; ct < 32; ++ct) {
            bf16x8 vf = *reinterpret_cast<const bf16x8*>(KV + ct * 512 + lr * 32 + ((lg ^ ((lr >> 1) & 3)) * 8));
            oacc[ct] = MFMA16(pf, vf, oacc[ct]);
        }
        __syncthreads();
    }

#pragma unroll
    for (int ct = 0; ct < 32; ++ct)
#pragma unroll
        for (int r = 0; r < 4; ++r) {
            int prow = rowbase + qt * 64 + w * 16 + lg * 4 + r;
            O[(size_t)prow * NC + ct * 16 + lr] = f2bf(oacc[ct][r] / s4[r]);
        }
}

extern "C" void kernel_launch(void* const* d_in, const int* in_sizes, int n_in,
                              void* d_out, int out_size, void* d_ws, size_t ws_size,
                              hipStream_t stream) {
    const float* left  = (const float*)d_in[0];
    const float* right = (const float*)d_in[1];
    const float* wq = (const float*)d_in[2];
    const float* wk = (const float*)d_in[3];
    const float* wv = (const float*)d_in[4];
    const float* w1 = (const float*)d_in[5];
    const float* bn_g = (const float*)d_in[6];
    const float* bn_b = (const float*)d_in[7];
    const float* bn_m = (const float*)d_in[8];
    const float* bn_v = (const float*)d_in[9];
    const float* w2 = (const float*)d_in[10];
    float* out = (float*)d_out;

    size_t off = 0;
    auto alloc = [&](size_t bytes) -> void* {
        void* p = (char*)d_ws + off;
        off += (bytes + 255) & ~(size_t)255;
        return p;
    };
    const size_t clb = (size_t)NPIX * NC * 2;        // 62.9 MB
    unsigned short* Lcl = (unsigned short*)alloc(clb);
    unsigned short* Rcl = (unsigned short*)alloc(clb);
    unsigned short* Qb  = (unsigned short*)alloc(clb);
    unsigned short* Kb  = (unsigned short*)alloc(clb);
    unsigned short* Vt  = (unsigned short*)alloc(clb);
    unsigned short* Wqb = (unsigned short*)alloc((size_t)NC * NC * 2);
    unsigned short* Wkb = (unsigned short*)alloc((size_t)NC * NC * 2);
    unsigned short* Wvb = (unsigned short*)alloc((size_t)NC * NC * 2);
    unsigned short* W1b = (unsigned short*)alloc((size_t)NOUT * 1024 * 2);
    unsigned short* W2b = (unsigned short*)alloc((size_t)NOUT * NOUT * 2);
    unsigned short* AO = Rcl;   // attention output aliases Rcl (dead after projections)
    unsigned short* Yb = Qb;    // y aliases Qb (dead after attention)

    k_cast<<<dim3((NC * NC + 255) / 256), 256, 0, stream>>>(wq, Wqb, NC * NC);
    k_cast<<<dim3((NC * NC + 255) / 256), 256, 0, stream>>>(wk, Wkb, NC * NC);
    k_cast<<<dim3((NC * NC + 255) / 256), 256, 0, stream>>>(wv, Wvb, NC * NC);
    k_cast<<<dim3((NOUT * 1024 + 255) / 256), 256, 0, stream>>>(w1, W1b, NOUT * 1024);
    k_cast<<<dim3((NOUT * NOUT + 255) / 256), 256, 0, stream>>>(w2, W2b, NOUT * NOUT);

    k_transpose<<<dim3(PH / 64, NC / 64, 4), 256, 0, stream>>>(left, right, Lcl, Rcl);

    // Q: [61440,512] = Lcl @ Wq^T
    k_gemm<0><<<dim3(1920), 256, 0, stream>>>(Lcl, nullptr, Wqb, Qb, nullptr, nullptr, nullptr, nullptr, nullptr);
    // K: Rcl @ Wk^T
    k_gemm<1><<<dim3(1920), 256, 0, stream>>>(Rcl, nullptr, Wkb, Kb, nullptr, nullptr, nullptr, nullptr, nullptr);
    // V^T: Wv @ Rcl^T
    k_gemm<2><<<dim3(1920), 256, 0, stream>>>(Wvb, nullptr, Rcl, Vt, nullptr, nullptr, nullptr, nullptr, nullptr);

    k_attn<<<dim3(960), 256, 0, stream>>>(Qb, Kb, Vt, AO);

    // w1 + BN + LeakyReLU: concat K
    k_gemm<3><<<dim3(960), 256, 0, stream>>>(Lcl, AO, W1b, Yb, nullptr, bn_g, bn_b, bn_m, bn_v);

    // w2 transposed-compute, f32 channels-first out
    k_gemm<4><<<dim3(960), 256, 0, stream>>>(W2b, nullptr, Yb, nullptr, out, nullptr, nullptr, nullptr, nullptr);
}